// Round 3
// baseline (1507.163 us; speedup 1.0000x reference)
//
#include <hip/hip_runtime.h>

#define NN 50000
#define FIN 512
#define HID 64
#define NC 32

// ---------------------------------------------------------------------------
// Kernel 1: R0 = relu(x @ W1 + b1).  x:(NN,512) W1:(512,64)
// 64x64 tile per 256-thread block, 4x4 micro-tile per thread, BK=16.
// ---------------------------------------------------------------------------
__global__ void gemm1_relu_kernel(const float* __restrict__ x,
                                  const float* __restrict__ W1,
                                  const float* __restrict__ b1,
                                  float* __restrict__ R0) {
  __shared__ float xs[64][17];   // +1 pad breaks 16-way bank conflict
  __shared__ float wsm[16][64];
  const int t = threadIdx.x;
  const int row0 = blockIdx.x * 64;
  const int tr = t >> 4, tc = t & 15;
  const int lr = t >> 2, lk = (t & 3) << 2;  // x-tile load coords
  const int wk = t >> 4, wc = (t & 15) << 2; // W-tile load coords
  float acc[4][4] = {};
  for (int k0 = 0; k0 < FIN; k0 += 16) {
    float4 xv = make_float4(0.f, 0.f, 0.f, 0.f);
    const int grow = row0 + lr;
    if (grow < NN) xv = *(const float4*)(x + (size_t)grow * FIN + k0 + lk);
    xs[lr][lk + 0] = xv.x; xs[lr][lk + 1] = xv.y;
    xs[lr][lk + 2] = xv.z; xs[lr][lk + 3] = xv.w;
    *(float4*)(&wsm[wk][wc]) = *(const float4*)(W1 + (size_t)(k0 + wk) * HID + wc);
    __syncthreads();
#pragma unroll
    for (int kk = 0; kk < 16; ++kk) {
      const float a0 = xs[tr * 4 + 0][kk];
      const float a1 = xs[tr * 4 + 1][kk];
      const float a2 = xs[tr * 4 + 2][kk];
      const float a3 = xs[tr * 4 + 3][kk];
      const float4 b = *(const float4*)(&wsm[kk][tc * 4]);
      acc[0][0] += a0 * b.x; acc[0][1] += a0 * b.y; acc[0][2] += a0 * b.z; acc[0][3] += a0 * b.w;
      acc[1][0] += a1 * b.x; acc[1][1] += a1 * b.y; acc[1][2] += a1 * b.z; acc[1][3] += a1 * b.w;
      acc[2][0] += a2 * b.x; acc[2][1] += a2 * b.y; acc[2][2] += a2 * b.z; acc[2][3] += a2 * b.w;
      acc[3][0] += a3 * b.x; acc[3][1] += a3 * b.y; acc[3][2] += a3 * b.z; acc[3][3] += a3 * b.w;
    }
    __syncthreads();
  }
  const float4 bb = *(const float4*)(b1 + tc * 4);
#pragma unroll
  for (int i = 0; i < 4; ++i) {
    const int grow = row0 + tr * 4 + i;
    if (grow < NN) {
      float4 o;
      o.x = fmaxf(acc[i][0] + bb.x, 0.f);
      o.y = fmaxf(acc[i][1] + bb.y, 0.f);
      o.z = fmaxf(acc[i][2] + bb.z, 0.f);
      o.w = fmaxf(acc[i][3] + bb.w, 0.f);
      *(float4*)(R0 + (size_t)grow * HID + tc * 4) = o;
    }
  }
}

// ---------------------------------------------------------------------------
// Kernel 2: segmented SpMM.  Edges are sorted by (row,col); padding has
// val=0 so it contributes nothing.  One wave per edge chunk, lane=feature.
// In-register accumulate while row unchanged; atomicAdd at row boundaries.
// ---------------------------------------------------------------------------
__global__ void spmm_kernel(const int* __restrict__ row, const int* __restrict__ col,
                            const float* __restrict__ val, const int E, const int epw,
                            const float* __restrict__ Rin, float* __restrict__ Rout) {
  const int wave = (int)((blockIdx.x * blockDim.x + threadIdx.x) >> 6);
  const int lane = threadIdx.x & 63;
  long s = (long)wave * epw;
  if (s >= E) return;
  long e_end = s + epw;
  if (e_end > E) e_end = E;
  int cur = row[s];
  float acc = 0.f;
  for (long e = s; e < e_end; ++e) {
    const int r = row[e];
    const int c = col[e];
    const float v = val[e];
    if (r != cur) {                       // wave-uniform branch
      atomicAdd(Rout + (size_t)cur * HID + lane, acc);
      acc = 0.f;
      cur = r;
    }
    acc += v * Rin[(size_t)c * HID + lane];   // 256B coalesced gather
  }
  atomicAdd(Rout + (size_t)cur * HID + lane, acc);
}

// ---------------------------------------------------------------------------
// Kernel 3: elementwise max (float4); O may alias B (in-place safe).
// ---------------------------------------------------------------------------
__global__ void max_kernel(const float* __restrict__ A, const float* B,
                           float* O, const int n4) {
  const int i = blockIdx.x * blockDim.x + threadIdx.x;
  if (i < n4) {
    const float4 a = ((const float4*)A)[i];
    const float4 b = ((const float4*)B)[i];
    float4 o;
    o.x = fmaxf(a.x, b.x); o.y = fmaxf(a.y, b.y);
    o.z = fmaxf(a.z, b.z); o.w = fmaxf(a.w, b.w);
    ((float4*)O)[i] = o;
  }
}

// ---------------------------------------------------------------------------
// Kernel 4: out = log_softmax(concat(R0,R1,R2) @ W2 + b2)
// 8 nodes per 256-thread block; 32 lanes per node (lane = class).
// ---------------------------------------------------------------------------
__global__ void final_kernel(const float* __restrict__ R0, const float* __restrict__ R1,
                             const float* __restrict__ R2, const float* __restrict__ W2,
                             const float* __restrict__ b2, float* __restrict__ out) {
  __shared__ float w2s[192 * 32];  // 24 KB
  __shared__ float fs[8][192];     // 6 KB
  const int t = threadIdx.x;
  const int node0 = blockIdx.x * 8;
  for (int i = t; i < 192 * 32; i += 256) w2s[i] = W2[i];
  for (int i = t; i < 8 * 192; i += 256) {
    const int n = i / 192, k = i % 192;
    const int node = node0 + n;
    float v = 0.f;
    if (node < NN) {
      v = (k < 64)  ? R0[(size_t)node * 64 + k]
        : (k < 128) ? R1[(size_t)node * 64 + (k - 64)]
                    : R2[(size_t)node * 64 + (k - 128)];
    }
    fs[n][k] = v;
  }
  __syncthreads();
  const int n = t >> 5, c = t & 31;
  const int node = node0 + n;
  float acc = b2[c];
#pragma unroll 8
  for (int k = 0; k < 192; ++k) acc += fs[n][k] * w2s[k * 32 + c];
  float m = acc;
  for (int off = 16; off; off >>= 1) m = fmaxf(m, __shfl_xor(m, off, 32));
  const float ex = __expf(acc - m);
  float ssum = ex;
  for (int off = 16; off; off >>= 1) ssum += __shfl_xor(ssum, off, 32);
  if (node < NN) out[(size_t)node * 32 + c] = (acc - m) - __logf(ssum);
}

// ---------------------------------------------------------------------------
extern "C" void kernel_launch(void* const* d_in, const int* in_sizes, int n_in,
                              void* d_out, int out_size, void* d_ws, size_t ws_size,
                              hipStream_t stream) {
  const float* x  = (const float*)d_in[0];
  const int*   e1r = (const int*)d_in[1];
  const int*   e1c = (const int*)d_in[2];
  const float* e1v = (const float*)d_in[3];
  const int*   e2r = (const int*)d_in[4];
  const int*   e2c = (const int*)d_in[5];
  const float* e2v = (const float*)d_in[6];
  const float* W1 = (const float*)d_in[7];
  const float* b1 = (const float*)d_in[8];
  const float* W2 = (const float*)d_in[9];
  const float* b2 = (const float*)d_in[10];
  float* out = (float*)d_out;
  const int E1 = in_sizes[1];
  const int E2 = in_sizes[4];

  float* wsf = (float*)d_ws;
  const size_t RSZ = (size_t)NN * HID;  // 3.2M floats
  if (ws_size < 4 * RSZ * sizeof(float)) return;  // fail loud (wrong out), not OOB
  float* R0  = wsf;
  float* Rr1 = wsf + RSZ;
  float* Rr2 = wsf + 2 * RSZ;
  float* T   = wsf + 3 * RSZ;

  // 1) R0 = relu(x @ W1 + b1)
  gemm1_relu_kernel<<<(NN + 63) / 64, 256, 0, stream>>>(x, W1, b1, R0);

  // 2) two rounds of dual SpMM + max (in-place max into the round's dst)
  const int EPW1 = 256, EPW2 = 768;
  const int nw1 = (E1 + EPW1 - 1) / EPW1;
  const int nw2 = (E2 + EPW2 - 1) / EPW2;
  const int nb1 = (nw1 + 3) / 4;   // 4 waves per 256-thread block
  const int nb2 = (nw2 + 3) / 4;
  const int maxb = ((int)(RSZ / 4) + 255) / 256;

  const float* Rin = R0;
  float* Rdst[2] = {Rr1, Rr2};
  for (int round = 0; round < 2; ++round) {
    float* dst = Rdst[round];
    hipMemsetAsync(T, 0, RSZ * sizeof(float), stream);
    hipMemsetAsync(dst, 0, RSZ * sizeof(float), stream);
    spmm_kernel<<<nb1, 256, 0, stream>>>(e1r, e1c, e1v, E1, EPW1, Rin, T);
    spmm_kernel<<<nb2, 256, 0, stream>>>(e2r, e2c, e2v, E2, EPW2, Rin, dst);
    max_kernel<<<maxb, 256, 0, stream>>>(T, dst, dst, (int)(RSZ / 4));
    Rin = dst;
  }

  // 3) final classifier + log_softmax
  final_kernel<<<(NN + 7) / 8, 256, 0, stream>>>(R0, Rr1, Rr2, W2, b2, out);
}

// Round 4
// 618.331 us; speedup vs baseline: 2.4375x; 2.4375x over previous
//
#include <hip/hip_runtime.h>

#define NN 50000
#define FIN 512
#define HID 64
#define NC 32

// ---------------------------------------------------------------------------
// Kernel 1: R0 = relu(x @ W1 + b1).  x:(NN,512) W1:(512,64)
// 64x64 tile per 256-thread block, 4x4 micro-tile per thread, BK=16.
// ---------------------------------------------------------------------------
__global__ void gemm1_relu_kernel(const float* __restrict__ x,
                                  const float* __restrict__ W1,
                                  const float* __restrict__ b1,
                                  float* __restrict__ R0) {
  __shared__ float xs[64][17];   // +1 pad breaks 16-way bank conflict
  __shared__ float wsm[16][64];
  const int t = threadIdx.x;
  const int row0 = blockIdx.x * 64;
  const int tr = t >> 4, tc = t & 15;
  const int lr = t >> 2, lk = (t & 3) << 2;  // x-tile load coords
  const int wk = t >> 4, wc = (t & 15) << 2; // W-tile load coords
  float acc[4][4] = {};
  for (int k0 = 0; k0 < FIN; k0 += 16) {
    float4 xv = make_float4(0.f, 0.f, 0.f, 0.f);
    const int grow = row0 + lr;
    if (grow < NN) xv = *(const float4*)(x + (size_t)grow * FIN + k0 + lk);
    xs[lr][lk + 0] = xv.x; xs[lr][lk + 1] = xv.y;
    xs[lr][lk + 2] = xv.z; xs[lr][lk + 3] = xv.w;
    *(float4*)(&wsm[wk][wc]) = *(const float4*)(W1 + (size_t)(k0 + wk) * HID + wc);
    __syncthreads();
#pragma unroll
    for (int kk = 0; kk < 16; ++kk) {
      const float a0 = xs[tr * 4 + 0][kk];
      const float a1 = xs[tr * 4 + 1][kk];
      const float a2 = xs[tr * 4 + 2][kk];
      const float a3 = xs[tr * 4 + 3][kk];
      const float4 b = *(const float4*)(&wsm[kk][tc * 4]);
      acc[0][0] += a0 * b.x; acc[0][1] += a0 * b.y; acc[0][2] += a0 * b.z; acc[0][3] += a0 * b.w;
      acc[1][0] += a1 * b.x; acc[1][1] += a1 * b.y; acc[1][2] += a1 * b.z; acc[1][3] += a1 * b.w;
      acc[2][0] += a2 * b.x; acc[2][1] += a2 * b.y; acc[2][2] += a2 * b.z; acc[2][3] += a2 * b.w;
      acc[3][0] += a3 * b.x; acc[3][1] += a3 * b.y; acc[3][2] += a3 * b.z; acc[3][3] += a3 * b.w;
    }
    __syncthreads();
  }
  const float4 bb = *(const float4*)(b1 + tc * 4);
#pragma unroll
  for (int i = 0; i < 4; ++i) {
    const int grow = row0 + tr * 4 + i;
    if (grow < NN) {
      float4 o;
      o.x = fmaxf(acc[i][0] + bb.x, 0.f);
      o.y = fmaxf(acc[i][1] + bb.y, 0.f);
      o.z = fmaxf(acc[i][2] + bb.z, 0.f);
      o.w = fmaxf(acc[i][3] + bb.w, 0.f);
      *(float4*)(R0 + (size_t)grow * HID + tc * 4) = o;
    }
  }
}

// ---------------------------------------------------------------------------
// Kernel 2: build CSR rowptr from row-sorted COO with zero-val padding.
// rv(e) = (val!=0) ? row[e] : NN is monotone non-decreasing; thread e fills
// all rowptr entries in (rv(e-1), rv(e)].  Every entry [0..NN] written.
// ---------------------------------------------------------------------------
__global__ void build_rowptr_kernel(const int* __restrict__ row,
                                    const float* __restrict__ val,
                                    const int E, int* __restrict__ ptr) {
  const int e = blockIdx.x * blockDim.x + threadIdx.x;
  if (e >= E) return;
  const int c = (val[e] != 0.f) ? row[e] : NN;
  const int p = (e == 0) ? -1 : ((val[e - 1] != 0.f) ? row[e - 1] : NN);
  for (int r = p + 1; r <= c; ++r) ptr[r] = e;
  if (e == E - 1) {                 // no-padding fallback
    for (int r = c + 1; r <= NN; ++r) ptr[r] = E;
  }
}

// ---------------------------------------------------------------------------
// Branch-free segmented dot: 8-wide unrolled, 4 accumulators, 8 gathers in
// flight.  Rl = Rin + lane; gather stride HID floats.
// ---------------------------------------------------------------------------
__device__ __forceinline__ float seg_dot(const int* __restrict__ col,
                                         const float* __restrict__ val,
                                         int s, int t, const float* __restrict__ Rl) {
  float a0 = 0.f, a1 = 0.f, a2 = 0.f, a3 = 0.f;
  int e = s;
  for (; e + 8 <= t; e += 8) {
    const int c0 = col[e + 0], c1 = col[e + 1], c2 = col[e + 2], c3 = col[e + 3];
    const int c4 = col[e + 4], c5 = col[e + 5], c6 = col[e + 6], c7 = col[e + 7];
    const float v0 = val[e + 0], v1 = val[e + 1], v2 = val[e + 2], v3 = val[e + 3];
    const float v4 = val[e + 4], v5 = val[e + 5], v6 = val[e + 6], v7 = val[e + 7];
    const float g0 = Rl[(size_t)c0 << 6], g1 = Rl[(size_t)c1 << 6];
    const float g2 = Rl[(size_t)c2 << 6], g3 = Rl[(size_t)c3 << 6];
    const float g4 = Rl[(size_t)c4 << 6], g5 = Rl[(size_t)c5 << 6];
    const float g6 = Rl[(size_t)c6 << 6], g7 = Rl[(size_t)c7 << 6];
    a0 += v0 * g0; a1 += v1 * g1; a2 += v2 * g2; a3 += v3 * g3;
    a0 += v4 * g4; a1 += v5 * g5; a2 += v6 * g6; a3 += v7 * g7;
  }
  for (; e < t; ++e) a0 += val[e] * Rl[(size_t)col[e] << 6];
  return (a0 + a1) + (a2 + a3);
}

// ---------------------------------------------------------------------------
// Kernel 3: fused dual-SpMM + max.  One wave per row, lane = feature.
// No atomics, no memset, no separate max pass.
// ---------------------------------------------------------------------------
__global__ void agg_kernel(const int* __restrict__ c1, const float* __restrict__ v1,
                           const int* __restrict__ p1,
                           const int* __restrict__ c2, const float* __restrict__ v2,
                           const int* __restrict__ p2,
                           const float* __restrict__ Rin, float* __restrict__ Rout) {
  const int wid = (int)((blockIdx.x * blockDim.x + threadIdx.x) >> 6);
  if (wid >= NN) return;
  const int lane = threadIdx.x & 63;
  const float* Rl = Rin + lane;
  const float m1 = seg_dot(c1, v1, p1[wid], p1[wid + 1], Rl);
  const float m2 = seg_dot(c2, v2, p2[wid], p2[wid + 1], Rl);
  Rout[(size_t)wid * HID + lane] = fmaxf(m1, m2);
}

// ---------------------------------------------------------------------------
// Kernel 4: out = log_softmax(concat(R0,R1,R2) @ W2 + b2)
// 8 nodes per 256-thread block; 32 lanes per node (lane = class).
// ---------------------------------------------------------------------------
__global__ void final_kernel(const float* __restrict__ R0, const float* __restrict__ R1,
                             const float* __restrict__ R2, const float* __restrict__ W2,
                             const float* __restrict__ b2, float* __restrict__ out) {
  __shared__ float w2s[192 * 32];  // 24 KB
  __shared__ float fs[8][192];     // 6 KB
  const int t = threadIdx.x;
  const int node0 = blockIdx.x * 8;
  for (int i = t; i < 192 * 32; i += 256) w2s[i] = W2[i];
  for (int i = t; i < 8 * 192; i += 256) {
    const int n = i / 192, k = i % 192;
    const int node = node0 + n;
    float v = 0.f;
    if (node < NN) {
      v = (k < 64)  ? R0[(size_t)node * 64 + k]
        : (k < 128) ? R1[(size_t)node * 64 + (k - 64)]
                    : R2[(size_t)node * 64 + (k - 128)];
    }
    fs[n][k] = v;
  }
  __syncthreads();
  const int n = t >> 5, c = t & 31;
  const int node = node0 + n;
  float acc = b2[c];
#pragma unroll 8
  for (int k = 0; k < 192; ++k) acc += fs[n][k] * w2s[k * 32 + c];
  float m = acc;
  for (int off = 16; off; off >>= 1) m = fmaxf(m, __shfl_xor(m, off, 32));
  const float ex = __expf(acc - m);
  float ssum = ex;
  for (int off = 16; off; off >>= 1) ssum += __shfl_xor(ssum, off, 32);
  if (node < NN) out[(size_t)node * 32 + c] = (acc - m) - __logf(ssum);
}

// ---------------------------------------------------------------------------
extern "C" void kernel_launch(void* const* d_in, const int* in_sizes, int n_in,
                              void* d_out, int out_size, void* d_ws, size_t ws_size,
                              hipStream_t stream) {
  const float* x  = (const float*)d_in[0];
  const int*   e1r = (const int*)d_in[1];
  const int*   e1c = (const int*)d_in[2];
  const float* e1v = (const float*)d_in[3];
  const int*   e2r = (const int*)d_in[4];
  const int*   e2c = (const int*)d_in[5];
  const float* e2v = (const float*)d_in[6];
  const float* W1 = (const float*)d_in[7];
  const float* b1 = (const float*)d_in[8];
  const float* W2 = (const float*)d_in[9];
  const float* b2 = (const float*)d_in[10];
  float* out = (float*)d_out;
  const int E1 = in_sizes[1];
  const int E2 = in_sizes[4];

  float* wsf = (float*)d_ws;
  const size_t RSZ = (size_t)NN * HID;  // 3.2M floats
  const size_t need = 3 * RSZ * sizeof(float) + 2 * (NN + 1) * sizeof(int);
  if (ws_size < need) return;  // fail loud (wrong out), not OOB
  float* R0  = wsf;
  float* Rr1 = wsf + RSZ;
  float* Rr2 = wsf + 2 * RSZ;
  int*   p1  = (int*)(wsf + 3 * RSZ);
  int*   p2  = p1 + (NN + 1);

  // 1) R0 = relu(x @ W1 + b1)   [overlaps with rowptr builds on the stream]
  gemm1_relu_kernel<<<(NN + 63) / 64, 256, 0, stream>>>(x, W1, b1, R0);

  // 2) CSR rowptr for both graphs (once per call; reused by both rounds)
  build_rowptr_kernel<<<(E1 + 255) / 256, 256, 0, stream>>>(e1r, e1v, E1, p1);
  build_rowptr_kernel<<<(E2 + 255) / 256, 256, 0, stream>>>(e2r, e2v, E2, p2);

  // 3) two rounds of fused dual-SpMM + max
  const int aggb = (NN * 64 + 255) / 256;
  agg_kernel<<<aggb, 256, 0, stream>>>(e1c, e1v, p1, e2c, e2v, p2, R0,  Rr1);
  agg_kernel<<<aggb, 256, 0, stream>>>(e1c, e1v, p1, e2c, e2v, p2, Rr1, Rr2);

  // 4) final classifier + log_softmax
  final_kernel<<<(NN + 7) / 8, 256, 0, stream>>>(R0, Rr1, Rr2, W2, b2, out);
}

// Round 5
// 581.616 us; speedup vs baseline: 2.5913x; 1.0631x over previous
//
#include <hip/hip_runtime.h>

#define NN 50000
#define FIN 512
#define HID 64
#define NC 32

// ---------------------------------------------------------------------------
// Kernel 1: R0 = relu(x @ W1 + b1).  x:(NN,512) W1:(512,64)
// 64x64 tile per 256-thread block, 4x4 micro-tile per thread, BK=16.
// ---------------------------------------------------------------------------
__global__ void gemm1_relu_kernel(const float* __restrict__ x,
                                  const float* __restrict__ W1,
                                  const float* __restrict__ b1,
                                  float* __restrict__ R0) {
  __shared__ float xs[64][17];   // +1 pad breaks 16-way bank conflict
  __shared__ float wsm[16][64];
  const int t = threadIdx.x;
  const int row0 = blockIdx.x * 64;
  const int tr = t >> 4, tc = t & 15;
  const int lr = t >> 2, lk = (t & 3) << 2;  // x-tile load coords
  const int wk = t >> 4, wc = (t & 15) << 2; // W-tile load coords
  float acc[4][4] = {};
  for (int k0 = 0; k0 < FIN; k0 += 16) {
    float4 xv = make_float4(0.f, 0.f, 0.f, 0.f);
    const int grow = row0 + lr;
    if (grow < NN) xv = *(const float4*)(x + (size_t)grow * FIN + k0 + lk);
    xs[lr][lk + 0] = xv.x; xs[lr][lk + 1] = xv.y;
    xs[lr][lk + 2] = xv.z; xs[lr][lk + 3] = xv.w;
    *(float4*)(&wsm[wk][wc]) = *(const float4*)(W1 + (size_t)(k0 + wk) * HID + wc);
    __syncthreads();
#pragma unroll
    for (int kk = 0; kk < 16; ++kk) {
      const float a0 = xs[tr * 4 + 0][kk];
      const float a1 = xs[tr * 4 + 1][kk];
      const float a2 = xs[tr * 4 + 2][kk];
      const float a3 = xs[tr * 4 + 3][kk];
      const float4 b = *(const float4*)(&wsm[kk][tc * 4]);
      acc[0][0] += a0 * b.x; acc[0][1] += a0 * b.y; acc[0][2] += a0 * b.z; acc[0][3] += a0 * b.w;
      acc[1][0] += a1 * b.x; acc[1][1] += a1 * b.y; acc[1][2] += a1 * b.z; acc[1][3] += a1 * b.w;
      acc[2][0] += a2 * b.x; acc[2][1] += a2 * b.y; acc[2][2] += a2 * b.z; acc[2][3] += a2 * b.w;
      acc[3][0] += a3 * b.x; acc[3][1] += a3 * b.y; acc[3][2] += a3 * b.z; acc[3][3] += a3 * b.w;
    }
    __syncthreads();
  }
  const float4 bb = *(const float4*)(b1 + tc * 4);
#pragma unroll
  for (int i = 0; i < 4; ++i) {
    const int grow = row0 + tr * 4 + i;
    if (grow < NN) {
      float4 o;
      o.x = fmaxf(acc[i][0] + bb.x, 0.f);
      o.y = fmaxf(acc[i][1] + bb.y, 0.f);
      o.z = fmaxf(acc[i][2] + bb.z, 0.f);
      o.w = fmaxf(acc[i][3] + bb.w, 0.f);
      *(float4*)(R0 + (size_t)grow * HID + tc * 4) = o;
    }
  }
}

// ---------------------------------------------------------------------------
// Kernel 2: build CSR rowptr from row-sorted COO with zero-val padding.
// rv(e) = (val!=0) ? row[e] : NN is monotone non-decreasing; thread e fills
// all rowptr entries in (rv(e-1), rv(e)].  Every entry [0..NN] written.
// (e1 arrays are TRUNCATED, not padded — the e==E-1 fallback covers that.)
// ---------------------------------------------------------------------------
__global__ void build_rowptr_kernel(const int* __restrict__ row,
                                    const float* __restrict__ val,
                                    const int E, int* __restrict__ ptr) {
  const int e = blockIdx.x * blockDim.x + threadIdx.x;
  if (e >= E) return;
  const int c = (val[e] != 0.f) ? row[e] : NN;
  const int p = (e == 0) ? -1 : ((val[e - 1] != 0.f) ? row[e - 1] : NN);
  for (int r = p + 1; r <= c; ++r) ptr[r] = e;
  if (e == E - 1) {
    for (int r = c + 1; r <= NN; ++r) ptr[r] = E;
  }
}

// ---------------------------------------------------------------------------
// Segmented dot with SGPR-broadcast metadata.  Lanes cooperatively load BLK
// edges' (col,val); readlane makes each edge's metadata wave-uniform so the
// gather compiles to SALU base + global_load_dword with lane offset.
// Tail lanes masked via v=0 (contributes nothing); also prevents OOB metadata
// reads on the truncated e1 arrays.
// ---------------------------------------------------------------------------
template <int BLK>
__device__ __forceinline__ float seg_dot(const int* __restrict__ col,
                                         const float* __restrict__ val,
                                         int s, int t,
                                         const float* __restrict__ Rl,
                                         const int lane) {
  float a0 = 0.f, a1 = 0.f, a2 = 0.f, a3 = 0.f;
  for (int e = s; e < t; e += BLK) {
    const int idx = e + lane;
    int cl = 0;
    float vl = 0.f;
    if (lane < BLK && idx < t) { cl = col[idx]; vl = val[idx]; }
#pragma unroll
    for (int i = 0; i < BLK; i += 4) {
      const int c0 = __builtin_amdgcn_readlane(cl, i + 0);
      const int c1 = __builtin_amdgcn_readlane(cl, i + 1);
      const int c2 = __builtin_amdgcn_readlane(cl, i + 2);
      const int c3 = __builtin_amdgcn_readlane(cl, i + 3);
      const float w0 = __uint_as_float(__builtin_amdgcn_readlane((int)__float_as_uint(vl), i + 0));
      const float w1 = __uint_as_float(__builtin_amdgcn_readlane((int)__float_as_uint(vl), i + 1));
      const float w2 = __uint_as_float(__builtin_amdgcn_readlane((int)__float_as_uint(vl), i + 2));
      const float w3 = __uint_as_float(__builtin_amdgcn_readlane((int)__float_as_uint(vl), i + 3));
      a0 += w0 * Rl[(size_t)c0 * HID];
      a1 += w1 * Rl[(size_t)c1 * HID];
      a2 += w2 * Rl[(size_t)c2 * HID];
      a3 += w3 * Rl[(size_t)c3 * HID];
    }
  }
  return (a0 + a1) + (a2 + a3);
}

// ---------------------------------------------------------------------------
// Kernel 3: fused dual-SpMM + max.  One wave per row, lane = feature.
// ---------------------------------------------------------------------------
__global__ void agg_kernel(const int* __restrict__ c1, const float* __restrict__ v1,
                           const int* __restrict__ p1,
                           const int* __restrict__ c2, const float* __restrict__ v2,
                           const int* __restrict__ p2,
                           const float* __restrict__ Rin, float* __restrict__ Rout) {
  const int wid = (int)((blockIdx.x * blockDim.x + threadIdx.x) >> 6);
  if (wid >= NN) return;
  const int lane = threadIdx.x & 63;
  const float* Rl = Rin + lane;
  const float m1 = seg_dot<32>(c1, v1, p1[wid], p1[wid + 1], Rl, lane);
  const float m2 = seg_dot<64>(c2, v2, p2[wid], p2[wid + 1], Rl, lane);
  Rout[(size_t)wid * HID + lane] = fmaxf(m1, m2);
}

// ---------------------------------------------------------------------------
// Kernel 4: out = log_softmax(concat(R0,R1,R2) @ W2 + b2)
// 8 nodes per 256-thread block; 32 lanes per node (lane = class).
// ---------------------------------------------------------------------------
__global__ void final_kernel(const float* __restrict__ R0, const float* __restrict__ R1,
                             const float* __restrict__ R2, const float* __restrict__ W2,
                             const float* __restrict__ b2, float* __restrict__ out) {
  __shared__ float w2s[192 * 32];  // 24 KB
  __shared__ float fs[8][192];     // 6 KB
  const int t = threadIdx.x;
  const int node0 = blockIdx.x * 8;
  for (int i = t; i < 192 * 32; i += 256) w2s[i] = W2[i];
  for (int i = t; i < 8 * 192; i += 256) {
    const int n = i / 192, k = i % 192;
    const int node = node0 + n;
    float v = 0.f;
    if (node < NN) {
      v = (k < 64)  ? R0[(size_t)node * 64 + k]
        : (k < 128) ? R1[(size_t)node * 64 + (k - 64)]
                    : R2[(size_t)node * 64 + (k - 128)];
    }
    fs[n][k] = v;
  }
  __syncthreads();
  const int n = t >> 5, c = t & 31;
  const int node = node0 + n;
  float acc = b2[c];
#pragma unroll 8
  for (int k = 0; k < 192; ++k) acc += fs[n][k] * w2s[k * 32 + c];
  float m = acc;
  for (int off = 16; off; off >>= 1) m = fmaxf(m, __shfl_xor(m, off, 32));
  const float ex = __expf(acc - m);
  float ssum = ex;
  for (int off = 16; off; off >>= 1) ssum += __shfl_xor(ssum, off, 32);
  if (node < NN) out[(size_t)node * 32 + c] = (acc - m) - __logf(ssum);
}

// ---------------------------------------------------------------------------
extern "C" void kernel_launch(void* const* d_in, const int* in_sizes, int n_in,
                              void* d_out, int out_size, void* d_ws, size_t ws_size,
                              hipStream_t stream) {
  const float* x  = (const float*)d_in[0];
  const int*   e1r = (const int*)d_in[1];
  const int*   e1c = (const int*)d_in[2];
  const float* e1v = (const float*)d_in[3];
  const int*   e2r = (const int*)d_in[4];
  const int*   e2c = (const int*)d_in[5];
  const float* e2v = (const float*)d_in[6];
  const float* W1 = (const float*)d_in[7];
  const float* b1 = (const float*)d_in[8];
  const float* W2 = (const float*)d_in[9];
  const float* b2 = (const float*)d_in[10];
  float* out = (float*)d_out;
  const int E1 = in_sizes[1];
  const int E2 = in_sizes[4];

  float* wsf = (float*)d_ws;
  const size_t RSZ = (size_t)NN * HID;  // 3.2M floats
  const size_t need = 3 * RSZ * sizeof(float) + 2 * (NN + 1) * sizeof(int);
  if (ws_size < need) return;  // fail loud (wrong out), not OOB
  float* R0  = wsf;
  float* Rr1 = wsf + RSZ;
  float* Rr2 = wsf + 2 * RSZ;
  int*   p1  = (int*)(wsf + 3 * RSZ);
  int*   p2  = p1 + (NN + 1);

  // 1) R0 = relu(x @ W1 + b1)
  gemm1_relu_kernel<<<(NN + 63) / 64, 256, 0, stream>>>(x, W1, b1, R0);

  // 2) CSR rowptr for both graphs
  build_rowptr_kernel<<<(E1 + 255) / 256, 256, 0, stream>>>(e1r, e1v, E1, p1);
  build_rowptr_kernel<<<(E2 + 255) / 256, 256, 0, stream>>>(e2r, e2v, E2, p2);

  // 3) two rounds of fused dual-SpMM + max
  const int aggb = (NN * 64 + 255) / 256;
  agg_kernel<<<aggb, 256, 0, stream>>>(e1c, e1v, p1, e2c, e2v, p2, R0,  Rr1);
  agg_kernel<<<aggb, 256, 0, stream>>>(e1c, e1v, p1, e2c, e2v, p2, Rr1, Rr2);

  // 4) final classifier + log_softmax
  final_kernel<<<(NN + 7) / 8, 256, 0, stream>>>(R0, Rr1, Rr2, W2, b2, out);
}

// Round 6
// 431.541 us; speedup vs baseline: 3.4925x; 1.3478x over previous
//
#include <hip/hip_runtime.h>

#define NN 50000
#define FIN 512
#define HID 64
#define NC 32

__device__ __forceinline__ unsigned short bf16rne(float f) {
  unsigned u = __float_as_uint(f);
  u = u + 0x7FFFu + ((u >> 16) & 1u);
  return (unsigned short)(u >> 16);
}
__device__ __forceinline__ float bf2f(unsigned short s) {
  return __uint_as_float(((unsigned)s) << 16);
}

// ---------------------------------------------------------------------------
// Kernel 1: R0 = relu(x @ W1 + b1), written f32 (for final) + bf16 (for agg).
// 128x64 tile, BK=32, transposed x-tile in LDS (16B-aligned rows, no b128
// bank conflicts), 8x4 micro-tile per thread.
// ---------------------------------------------------------------------------
__global__ __launch_bounds__(256) void gemm1_relu_kernel(
    const float* __restrict__ x, const float* __restrict__ W1,
    const float* __restrict__ b1, float* __restrict__ R0,
    unsigned short* __restrict__ R0b) {
  __shared__ float xs[32][132];   // stride 132: 16B-aligned rows, banks rotate
  __shared__ float wsm[32][64];
  const int t = threadIdx.x;
  const int row0 = blockIdx.x * 128;
  const int tr = t >> 4, tc = t & 15;
  float acc[8][4] = {};
  for (int k0 = 0; k0 < FIN; k0 += 32) {
#pragma unroll
    for (int j = 0; j < 4; ++j) {          // x tile: 128 rows x 32 k, transposed
      const int idx = t + j * 256;
      const int r = idx & 127, kq = idx >> 7;
      float4 xv = make_float4(0.f, 0.f, 0.f, 0.f);
      const int grow = row0 + r;
      if (grow < NN) xv = *(const float4*)(x + (size_t)grow * FIN + k0 + kq * 4);
      xs[kq * 4 + 0][r] = xv.x; xs[kq * 4 + 1][r] = xv.y;
      xs[kq * 4 + 2][r] = xv.z; xs[kq * 4 + 3][r] = xv.w;
    }
#pragma unroll
    for (int j = 0; j < 2; ++j) {          // W tile: 32 k x 64 cols
      const int idx = t + j * 256;
      const int wr = idx >> 4, wc = (idx & 15) * 4;
      *(float4*)(&wsm[wr][wc]) = *(const float4*)(W1 + (size_t)(k0 + wr) * HID + wc);
    }
    __syncthreads();
#pragma unroll
    for (int kk = 0; kk < 32; ++kk) {
      const float4 a0 = *(const float4*)(&xs[kk][tr * 8]);
      const float4 a1 = *(const float4*)(&xs[kk][tr * 8 + 4]);
      const float4 b  = *(const float4*)(&wsm[kk][tc * 4]);
      const float av[8] = {a0.x, a0.y, a0.z, a0.w, a1.x, a1.y, a1.z, a1.w};
      const float bv[4] = {b.x, b.y, b.z, b.w};
#pragma unroll
      for (int i = 0; i < 8; ++i)
#pragma unroll
        for (int j = 0; j < 4; ++j) acc[i][j] = fmaf(av[i], bv[j], acc[i][j]);
    }
    __syncthreads();
  }
  const float4 bb = *(const float4*)(b1 + tc * 4);
#pragma unroll
  for (int i = 0; i < 8; ++i) {
    const int grow = row0 + tr * 8 + i;
    if (grow < NN) {
      float4 o;
      o.x = fmaxf(acc[i][0] + bb.x, 0.f);
      o.y = fmaxf(acc[i][1] + bb.y, 0.f);
      o.z = fmaxf(acc[i][2] + bb.z, 0.f);
      o.w = fmaxf(acc[i][3] + bb.w, 0.f);
      *(float4*)(R0 + (size_t)grow * HID + tc * 4) = o;
      uint2 p;
      p.x = ((unsigned)bf16rne(o.y) << 16) | (unsigned)bf16rne(o.x);
      p.y = ((unsigned)bf16rne(o.w) << 16) | (unsigned)bf16rne(o.z);
      *(uint2*)(R0b + (size_t)grow * HID + tc * 4) = p;
    }
  }
}

// ---------------------------------------------------------------------------
// Kernel 2: build CSR rowptr from row-sorted COO with zero-val padding.
// ---------------------------------------------------------------------------
__global__ void build_rowptr_kernel(const int* __restrict__ row,
                                    const float* __restrict__ val,
                                    const int E, int* __restrict__ ptr) {
  const int e = blockIdx.x * blockDim.x + threadIdx.x;
  if (e >= E) return;
  const int c = (val[e] != 0.f) ? row[e] : NN;
  const int p = (e == 0) ? -1 : ((val[e - 1] != 0.f) ? row[e - 1] : NN);
  for (int r = p + 1; r <= c; ++r) ptr[r] = e;
  if (e == E - 1) {
    for (int r = c + 1; r <= NN; ++r) ptr[r] = E;
  }
}

// ---------------------------------------------------------------------------
// Segmented dot, 2 edges per VMEM on bf16 R.  Metadata staged to wave-private
// LDS (ds_read_b64 broadcast per half-wave); lanes 0-31 process even edges,
// 32-63 odd edges, each lane covering 2 features (one dword = 2 bf16).
// Returns per-lane partial sums (even/odd-edge halves combined by caller).
// ---------------------------------------------------------------------------
template <int BLK>
__device__ __forceinline__ float2 seg_pair(const int* __restrict__ col,
                                           const float* __restrict__ val,
                                           int s, int t,
                                           const unsigned short* __restrict__ Rb,
                                           uint2* __restrict__ meta,
                                           const int lane, const unsigned laneoff) {
  float a0 = 0.f, a1 = 0.f;
  const int half = lane >> 5;
  for (int e = s; e < t; e += BLK) {
    const int idx = e + lane;
    if (lane < BLK) {
      unsigned cw = 0u, vw = 0u;
      if (idx < t) { cw = (unsigned)col[idx]; vw = __float_as_uint(val[idx]); }
      meta[lane] = make_uint2(cw, vw);
    }
#pragma unroll
    for (int i = 0; i < BLK / 2; ++i) {
      const uint2 m = meta[2 * i + half];
      const float v = __uint_as_float(m.y);
      const unsigned gw =
          *(const unsigned*)((const char*)Rb + ((size_t)m.x * 128u) + laneoff);
      a0 = fmaf(v, __uint_as_float(gw << 16), a0);
      a1 = fmaf(v, __uint_as_float(gw & 0xffff0000u), a1);
    }
  }
  return make_float2(a0, a1);
}

// ---------------------------------------------------------------------------
// Kernel 3: fused dual-SpMM + max.  One wave per row.
// OUTMODE 0: write bf16 only (round 1).  OUTMODE 1: write f32 only (round 2).
// ---------------------------------------------------------------------------
template <int OUTMODE>
__global__ __launch_bounds__(256) void agg_kernel(
    const int* __restrict__ c1, const float* __restrict__ v1, const int* __restrict__ p1,
    const int* __restrict__ c2, const float* __restrict__ v2, const int* __restrict__ p2,
    const unsigned short* __restrict__ Rb,
    float* __restrict__ outf, unsigned short* __restrict__ outb) {
  __shared__ uint2 meta[4][64];
  const int wslot = threadIdx.x >> 6;
  const int wid = (int)((blockIdx.x * blockDim.x + threadIdx.x) >> 6);
  if (wid >= NN) return;
  const int lane = threadIdx.x & 63;
  const unsigned laneoff = (unsigned)(lane & 31) << 2;
  const float2 h1 = seg_pair<16>(c1, v1, p1[wid], p1[wid + 1], Rb, meta[wslot], lane, laneoff);
  const float2 h2 = seg_pair<64>(c2, v2, p2[wid], p2[wid + 1], Rb, meta[wslot], lane, laneoff);
  const float t1e = h1.x + __shfl_xor(h1.x, 32, 64);
  const float t1o = h1.y + __shfl_xor(h1.y, 32, 64);
  const float t2e = h2.x + __shfl_xor(h2.x, 32, 64);
  const float t2o = h2.y + __shfl_xor(h2.y, 32, 64);
  const int half = lane >> 5;
  const float r = half ? fmaxf(t1o, t2o) : fmaxf(t1e, t2e);
  const size_t oidx = (size_t)wid * HID + 2 * (lane & 31) + half;
  if (OUTMODE == 0) outb[oidx] = bf16rne(r);
  else              outf[oidx] = r;
}

// ---------------------------------------------------------------------------
// Kernel 4: out = log_softmax(concat(R0, R1(bf16), R2) @ W2 + b2)
// ---------------------------------------------------------------------------
__global__ void final_kernel(const float* __restrict__ R0,
                             const unsigned short* __restrict__ R1b,
                             const float* __restrict__ R2,
                             const float* __restrict__ W2,
                             const float* __restrict__ b2, float* __restrict__ out) {
  __shared__ float w2s[192 * 32];  // 24 KB
  __shared__ float fs[8][192];     // 6 KB
  const int t = threadIdx.x;
  const int node0 = blockIdx.x * 8;
  for (int i = t; i < 192 * 32; i += 256) w2s[i] = W2[i];
  for (int i = t; i < 8 * 192; i += 256) {
    const int n = i / 192, k = i % 192;
    const int node = node0 + n;
    float v = 0.f;
    if (node < NN) {
      v = (k < 64)  ? R0[(size_t)node * 64 + k]
        : (k < 128) ? bf2f(R1b[(size_t)node * 64 + (k - 64)])
                    : R2[(size_t)node * 64 + (k - 128)];
    }
    fs[n][k] = v;
  }
  __syncthreads();
  const int n = t >> 5, c = t & 31;
  const int node = node0 + n;
  float acc = b2[c];
#pragma unroll 8
  for (int k = 0; k < 192; ++k) acc += fs[n][k] * w2s[k * 32 + c];
  float m = acc;
  for (int off = 16; off; off >>= 1) m = fmaxf(m, __shfl_xor(m, off, 32));
  const float ex = __expf(acc - m);
  float ssum = ex;
  for (int off = 16; off; off >>= 1) ssum += __shfl_xor(ssum, off, 32);
  if (node < NN) out[(size_t)node * 32 + c] = (acc - m) - __logf(ssum);
}

// ---------------------------------------------------------------------------
extern "C" void kernel_launch(void* const* d_in, const int* in_sizes, int n_in,
                              void* d_out, int out_size, void* d_ws, size_t ws_size,
                              hipStream_t stream) {
  const float* x  = (const float*)d_in[0];
  const int*   e1r = (const int*)d_in[1];
  const int*   e1c = (const int*)d_in[2];
  const float* e1v = (const float*)d_in[3];
  const int*   e2r = (const int*)d_in[4];
  const int*   e2c = (const int*)d_in[5];
  const float* e2v = (const float*)d_in[6];
  const float* W1 = (const float*)d_in[7];
  const float* b1 = (const float*)d_in[8];
  const float* W2 = (const float*)d_in[9];
  const float* b2 = (const float*)d_in[10];
  float* out = (float*)d_out;
  const int E1 = in_sizes[1];
  const int E2 = in_sizes[4];

  char* wsb = (char*)d_ws;
  const size_t RSZ = (size_t)NN * HID;  // 3.2M elements
  // layout (bytes): R0 f32 | R2 f32 | R0b bf16 | R1b bf16 | p1 | p2
  const size_t need = RSZ * 4 * 2 + RSZ * 2 * 2 + 2 * (NN + 1) * sizeof(int);
  if (ws_size < need) return;  // fail loud (wrong out), not OOB
  float*          R0  = (float*)wsb;
  float*          R2  = (float*)(wsb + RSZ * 4);
  unsigned short* R0b = (unsigned short*)(wsb + RSZ * 8);
  unsigned short* R1b = (unsigned short*)(wsb + RSZ * 8 + RSZ * 2);
  int*            p1  = (int*)(wsb + RSZ * 8 + RSZ * 4);
  int*            p2  = p1 + (NN + 1);

  // 1) R0 = relu(x @ W1 + b1)  (f32 + bf16 copies)
  gemm1_relu_kernel<<<(NN + 127) / 128, 256, 0, stream>>>(x, W1, b1, R0, R0b);

  // 2) CSR rowptr for both graphs
  build_rowptr_kernel<<<(E1 + 255) / 256, 256, 0, stream>>>(e1r, e1v, E1, p1);
  build_rowptr_kernel<<<(E2 + 255) / 256, 256, 0, stream>>>(e2r, e2v, E2, p2);

  // 3) two rounds of fused dual-SpMM + max (bf16 gathers)
  const int aggb = (NN * 64) / 256;
  agg_kernel<0><<<aggb, 256, 0, stream>>>(e1c, e1v, p1, e2c, e2v, p2, R0b, R0, R1b);
  agg_kernel<1><<<aggb, 256, 0, stream>>>(e1c, e1v, p1, e2c, e2v, p2, R1b, R2, R1b);

  // 4) final classifier + log_softmax
  final_kernel<<<(NN + 7) / 8, 256, 0, stream>>>(R0, R1b, R2, W2, b2, out);
}

// Round 7
// 398.877 us; speedup vs baseline: 3.7785x; 1.0819x over previous
//
#include <hip/hip_runtime.h>

#define NN 50000
#define FIN 512
#define HID 64
#define NC 32

typedef __attribute__((ext_vector_type(8))) short short8;
typedef __attribute__((ext_vector_type(4))) float f32x4;

__device__ __forceinline__ unsigned short bf16rne(float f) {
  unsigned u = __float_as_uint(f);
  u = u + 0x7FFFu + ((u >> 16) & 1u);
  return (unsigned short)(u >> 16);
}
__device__ __forceinline__ float bf2f(unsigned short s) {
  return __uint_as_float(((unsigned)s) << 16);
}
__device__ __forceinline__ unsigned cvt_pk_bf16(float lo, float hi) {
  unsigned d;
  asm("v_cvt_pk_bf16_f32 %0, %1, %2" : "=v"(d) : "v"(lo), "v"(hi));
  return d;
}

// ---------------------------------------------------------------------------
// Kernel 0: pack W1 (512x64 f32) into bf16 MFMA B-fragment layout.
// Fragment f = (ks*4 + nb)*64 + lane holds, for lane l:
//   col = nb*16 + (l&15),  k = ks*32 + (l>>4)*8 + j   (j = 0..7)
// ---------------------------------------------------------------------------
__global__ void w1_pack_kernel(const float* __restrict__ W1,
                               unsigned short* __restrict__ W1p) {
  const int t = blockIdx.x * blockDim.x + threadIdx.x;
  if (t >= 16 * 4 * 64) return;
  const int lane = t & 63, nb = (t >> 6) & 3, ks = t >> 8;
  const int col = nb * 16 + (lane & 15);
  const int k0 = ks * 32 + (lane >> 4) * 8;
  float f[8];
#pragma unroll
  for (int j = 0; j < 8; ++j) f[j] = W1[(size_t)(k0 + j) * HID + col];
  uint4 d;
  d.x = cvt_pk_bf16(f[0], f[1]);
  d.y = cvt_pk_bf16(f[2], f[3]);
  d.z = cvt_pk_bf16(f[4], f[5]);
  d.w = cvt_pk_bf16(f[6], f[7]);
  *(uint4*)(W1p + (size_t)t * 8) = d;
}

// ---------------------------------------------------------------------------
// Kernel 1: R0 = relu(x @ W1 + b1) via mfma_f32_16x16x32_bf16.
// 4 waves/block; wave w owns rows [blk*64 + w*16, +16), all 64 cols.
// A-fragments loaded directly from global x (per-lane (row, k-slice)) and
// packed to bf16 in-register; rows >= NN feed garbage that only lands in
// masked-out C rows (C row index == A row index).
// ---------------------------------------------------------------------------
__global__ __launch_bounds__(256) void gemm1_relu_kernel(
    const float* __restrict__ x, const unsigned short* __restrict__ W1p,
    const float* __restrict__ b1, float* __restrict__ R0,
    unsigned short* __restrict__ R0b) {
  const int t = threadIdx.x;
  const int w = t >> 6, lane = t & 63;
  const int arow = blockIdx.x * 64 + w * 16 + (lane & 15);
  const size_t rowoff = (arow < NN) ? (size_t)arow * FIN : 0;
  const float* xp = x + rowoff + (lane >> 4) * 8;
  f32x4 acc0 = {0.f, 0.f, 0.f, 0.f}, acc1 = acc0, acc2 = acc0, acc3 = acc0;
#pragma unroll
  for (int ks = 0; ks < 16; ++ks) {
    const float4 xa = *(const float4*)(xp);
    const float4 xb = *(const float4*)(xp + 4);
    xp += 32;
    uint4 ad;
    ad.x = cvt_pk_bf16(xa.x, xa.y);
    ad.y = cvt_pk_bf16(xa.z, xa.w);
    ad.z = cvt_pk_bf16(xb.x, xb.y);
    ad.w = cvt_pk_bf16(xb.z, xb.w);
    const short8 af = __builtin_bit_cast(short8, ad);
    const short8 b0 = *(const short8*)(W1p + ((size_t)(ks * 4 + 0) * 64 + lane) * 8);
    const short8 b1f = *(const short8*)(W1p + ((size_t)(ks * 4 + 1) * 64 + lane) * 8);
    const short8 b2 = *(const short8*)(W1p + ((size_t)(ks * 4 + 2) * 64 + lane) * 8);
    const short8 b3 = *(const short8*)(W1p + ((size_t)(ks * 4 + 3) * 64 + lane) * 8);
    acc0 = __builtin_amdgcn_mfma_f32_16x16x32_bf16(af, b0, acc0, 0, 0, 0);
    acc1 = __builtin_amdgcn_mfma_f32_16x16x32_bf16(af, b1f, acc1, 0, 0, 0);
    acc2 = __builtin_amdgcn_mfma_f32_16x16x32_bf16(af, b2, acc2, 0, 0, 0);
    acc3 = __builtin_amdgcn_mfma_f32_16x16x32_bf16(af, b3, acc3, 0, 0, 0);
  }
  // C/D layout: col = lane&15, row = (lane>>4)*4 + i   [m89]
  const int orow = blockIdx.x * 64 + w * 16 + (lane >> 4) * 4;
  const int ocol = lane & 15;
#define EPI(NB, ACC)                                                        \
  {                                                                         \
    const float bias = b1[NB * 16 + ocol];                                  \
    _Pragma("unroll") for (int i = 0; i < 4; ++i) {                         \
      const int r = orow + i;                                               \
      if (r < NN) {                                                         \
        const float v = fmaxf(ACC[i] + bias, 0.f);                          \
        R0[(size_t)r * HID + NB * 16 + ocol] = v;                           \
        R0b[(size_t)r * HID + NB * 16 + ocol] = bf16rne(v);                 \
      }                                                                     \
    }                                                                       \
  }
  EPI(0, acc0) EPI(1, acc1) EPI(2, acc2) EPI(3, acc3)
#undef EPI
}

// ---------------------------------------------------------------------------
// Kernel 2: build CSR rowptr from row-sorted COO with zero-val padding.
// ---------------------------------------------------------------------------
__global__ void build_rowptr_kernel(const int* __restrict__ row,
                                    const float* __restrict__ val,
                                    const int E, int* __restrict__ ptr) {
  const int e = blockIdx.x * blockDim.x + threadIdx.x;
  if (e >= E) return;
  const int c = (val[e] != 0.f) ? row[e] : NN;
  const int p = (e == 0) ? -1 : ((val[e - 1] != 0.f) ? row[e - 1] : NN);
  for (int r = p + 1; r <= c; ++r) ptr[r] = e;
  if (e == E - 1) {
    for (int r = c + 1; r <= NN; ++r) ptr[r] = E;
  }
}

// ---------------------------------------------------------------------------
// Segmented dot, 2 edges per VMEM on bf16 R.  Metadata staged to wave-private
// LDS; lanes 0-31 process even edges, 32-63 odd edges, each lane covering
// 2 features (one dword = 2 bf16).
// ---------------------------------------------------------------------------
template <int BLK>
__device__ __forceinline__ float2 seg_pair(const int* __restrict__ col,
                                           const float* __restrict__ val,
                                           int s, int t,
                                           const unsigned short* __restrict__ Rb,
                                           uint2* __restrict__ meta,
                                           const int lane, const unsigned laneoff) {
  float a0 = 0.f, a1 = 0.f;
  const int half = lane >> 5;
  for (int e = s; e < t; e += BLK) {
    const int idx = e + lane;
    if (lane < BLK) {
      unsigned cw = 0u, vw = 0u;
      if (idx < t) { cw = (unsigned)col[idx]; vw = __float_as_uint(val[idx]); }
      meta[lane] = make_uint2(cw, vw);
    }
#pragma unroll
    for (int i = 0; i < BLK / 2; ++i) {
      const uint2 m = meta[2 * i + half];
      const float v = __uint_as_float(m.y);
      const unsigned gw =
          *(const unsigned*)((const char*)Rb + ((size_t)m.x * 128u) + laneoff);
      a0 = fmaf(v, __uint_as_float(gw << 16), a0);
      a1 = fmaf(v, __uint_as_float(gw & 0xffff0000u), a1);
    }
  }
  return make_float2(a0, a1);
}

// ---------------------------------------------------------------------------
// Kernel 3: fused dual-SpMM + max.  One wave per row.
// OUTMODE 0: write bf16 only (round 1).  OUTMODE 1: write f32 only (round 2).
// ---------------------------------------------------------------------------
template <int OUTMODE>
__global__ __launch_bounds__(256) void agg_kernel(
    const int* __restrict__ c1, const float* __restrict__ v1, const int* __restrict__ p1,
    const int* __restrict__ c2, const float* __restrict__ v2, const int* __restrict__ p2,
    const unsigned short* __restrict__ Rb,
    float* __restrict__ outf, unsigned short* __restrict__ outb) {
  __shared__ uint2 meta[4][64];
  const int wslot = threadIdx.x >> 6;
  const int wid = (int)((blockIdx.x * blockDim.x + threadIdx.x) >> 6);
  if (wid >= NN) return;
  const int lane = threadIdx.x & 63;
  const unsigned laneoff = (unsigned)(lane & 31) << 2;
  const float2 h1 = seg_pair<16>(c1, v1, p1[wid], p1[wid + 1], Rb, meta[wslot], lane, laneoff);
  const float2 h2 = seg_pair<64>(c2, v2, p2[wid], p2[wid + 1], Rb, meta[wslot], lane, laneoff);
  const float t1e = h1.x + __shfl_xor(h1.x, 32, 64);
  const float t1o = h1.y + __shfl_xor(h1.y, 32, 64);
  const float t2e = h2.x + __shfl_xor(h2.x, 32, 64);
  const float t2o = h2.y + __shfl_xor(h2.y, 32, 64);
  const int half = lane >> 5;
  const float r = half ? fmaxf(t1o, t2o) : fmaxf(t1e, t2e);
  const size_t oidx = (size_t)wid * HID + 2 * (lane & 31) + half;
  if (OUTMODE == 0) outb[oidx] = bf16rne(r);
  else              outf[oidx] = r;
}

// ---------------------------------------------------------------------------
// Kernel 4: out = log_softmax(concat(R0, R1(bf16), R2) @ W2 + b2)
// ---------------------------------------------------------------------------
__global__ void final_kernel(const float* __restrict__ R0,
                             const unsigned short* __restrict__ R1b,
                             const float* __restrict__ R2,
                             const float* __restrict__ W2,
                             const float* __restrict__ b2, float* __restrict__ out) {
  __shared__ float w2s[192 * 32];  // 24 KB
  __shared__ float fs[8][192];     // 6 KB
  const int t = threadIdx.x;
  const int node0 = blockIdx.x * 8;
  for (int i = t; i < 192 * 32; i += 256) w2s[i] = W2[i];
  for (int i = t; i < 8 * 192; i += 256) {
    const int n = i / 192, k = i % 192;
    const int node = node0 + n;
    float v = 0.f;
    if (node < NN) {
      v = (k < 64)  ? R0[(size_t)node * 64 + k]
        : (k < 128) ? bf2f(R1b[(size_t)node * 64 + (k - 64)])
                    : R2[(size_t)node * 64 + (k - 128)];
    }
    fs[n][k] = v;
  }
  __syncthreads();
  const int n = t >> 5, c = t & 31;
  const int node = node0 + n;
  float acc = b2[c];
#pragma unroll 8
  for (int k = 0; k < 192; ++k) acc += fs[n][k] * w2s[k * 32 + c];
  float m = acc;
  for (int off = 16; off; off >>= 1) m = fmaxf(m, __shfl_xor(m, off, 32));
  const float ex = __expf(acc - m);
  float ssum = ex;
  for (int off = 16; off; off >>= 1) ssum += __shfl_xor(ssum, off, 32);
  if (node < NN) out[(size_t)node * 32 + c] = (acc - m) - __logf(ssum);
}

// ---------------------------------------------------------------------------
extern "C" void kernel_launch(void* const* d_in, const int* in_sizes, int n_in,
                              void* d_out, int out_size, void* d_ws, size_t ws_size,
                              hipStream_t stream) {
  const float* x  = (const float*)d_in[0];
  const int*   e1r = (const int*)d_in[1];
  const int*   e1c = (const int*)d_in[2];
  const float* e1v = (const float*)d_in[3];
  const int*   e2r = (const int*)d_in[4];
  const int*   e2c = (const int*)d_in[5];
  const float* e2v = (const float*)d_in[6];
  const float* W1 = (const float*)d_in[7];
  const float* b1 = (const float*)d_in[8];
  const float* W2 = (const float*)d_in[9];
  const float* b2 = (const float*)d_in[10];
  float* out = (float*)d_out;
  const int E1 = in_sizes[1];
  const int E2 = in_sizes[4];

  char* wsb = (char*)d_ws;
  const size_t RSZ = (size_t)NN * HID;  // 3.2M elements
  // layout (bytes): R0 f32 | R2 f32 | R0b bf16 | R1b bf16 | p1 | p2 | W1p
  const size_t need = RSZ * 4 * 2 + RSZ * 2 * 2 + 2 * (NN + 1) * sizeof(int)
                    + (size_t)FIN * HID * 2;
  if (ws_size < need) return;  // fail loud (wrong out), not OOB
  float*          R0  = (float*)wsb;
  float*          R2  = (float*)(wsb + RSZ * 4);
  unsigned short* R0b = (unsigned short*)(wsb + RSZ * 8);
  unsigned short* R1b = (unsigned short*)(wsb + RSZ * 8 + RSZ * 2);
  int*            p1  = (int*)(wsb + RSZ * 8 + RSZ * 4);
  int*            p2  = p1 + (NN + 1);
  unsigned short* W1p = (unsigned short*)(p2 + (NN + 1));

  // 0) pack W1 to bf16 fragment layout
  w1_pack_kernel<<<16, 256, 0, stream>>>(W1, W1p);

  // 1) R0 = relu(x @ W1 + b1)  (f32 + bf16 copies), MFMA
  gemm1_relu_kernel<<<(NN + 63) / 64, 256, 0, stream>>>(x, W1p, b1, R0, R0b);

  // 2) CSR rowptr for both graphs
  build_rowptr_kernel<<<(E1 + 255) / 256, 256, 0, stream>>>(e1r, e1v, E1, p1);
  build_rowptr_kernel<<<(E2 + 255) / 256, 256, 0, stream>>>(e2r, e2v, E2, p2);

  // 3) two rounds of fused dual-SpMM + max (bf16 gathers)
  const int aggb = (NN * 64) / 256;
  agg_kernel<0><<<aggb, 256, 0, stream>>>(e1c, e1v, p1, e2c, e2v, p2, R0b, R0, R1b);
  agg_kernel<1><<<aggb, 256, 0, stream>>>(e1c, e1v, p1, e2c, e2v, p2, R1b, R2, R1b);

  // 4) final classifier + log_softmax
  final_kernel<<<(NN + 7) / 8, 256, 0, stream>>>(R0, R1b, R2, W2, b2, out);
}

// Round 12
// 396.202 us; speedup vs baseline: 3.8040x; 1.0068x over previous
//
#include <hip/hip_runtime.h>

#define NN 50000
#define FIN 512
#define HID 64
#define NC 32

typedef __attribute__((ext_vector_type(8))) short short8;
typedef __attribute__((ext_vector_type(4))) float f32x4;

__device__ __forceinline__ unsigned short bf16rne(float f) {
  unsigned u = __float_as_uint(f);
  u = u + 0x7FFFu + ((u >> 16) & 1u);
  return (unsigned short)(u >> 16);
}
__device__ __forceinline__ float bf2f(unsigned short s) {
  return __uint_as_float(((unsigned)s) << 16);
}
__device__ __forceinline__ unsigned cvt_pk_bf16(float lo, float hi) {
  unsigned d;
  asm("v_cvt_pk_bf16_f32 %0, %1, %2" : "=v"(d) : "v"(lo), "v"(hi));
  return d;
}

// ---------------------------------------------------------------------------
// Kernel 0: pack W1 (512x64 f32) into bf16 MFMA B-fragment layout.
// Fragment f = (ks*4 + nb)*64 + lane holds, for lane l:
//   col = nb*16 + (l&15),  k = ks*32 + (l>>4)*8 + j   (j = 0..7)
// ---------------------------------------------------------------------------
__global__ void w1_pack_kernel(const float* __restrict__ W1,
                               unsigned short* __restrict__ W1p) {
  const int t = blockIdx.x * blockDim.x + threadIdx.x;
  if (t >= 16 * 4 * 64) return;
  const int lane = t & 63, nb = (t >> 6) & 3, ks = t >> 8;
  const int col = nb * 16 + (lane & 15);
  const int k0 = ks * 32 + (lane >> 4) * 8;
  float f[8];
#pragma unroll
  for (int j = 0; j < 8; ++j) f[j] = W1[(size_t)(k0 + j) * HID + col];
  uint4 d;
  d.x = cvt_pk_bf16(f[0], f[1]);
  d.y = cvt_pk_bf16(f[2], f[3]);
  d.z = cvt_pk_bf16(f[4], f[5]);
  d.w = cvt_pk_bf16(f[6], f[7]);
  *(uint4*)(W1p + (size_t)t * 8) = d;
}

// ---------------------------------------------------------------------------
// Kernel 1: R0 = relu(x @ W1 + b1) via mfma_f32_16x16x32_bf16.
// 4 waves/block; wave w owns rows [blk*64 + w*16, +16), all 64 cols.
// (Round-6 version verbatim — known good.)
// ---------------------------------------------------------------------------
__global__ __launch_bounds__(256) void gemm1_relu_kernel(
    const float* __restrict__ x, const unsigned short* __restrict__ W1p,
    const float* __restrict__ b1, float* __restrict__ R0,
    unsigned short* __restrict__ R0b) {
  const int t = threadIdx.x;
  const int w = t >> 6, lane = t & 63;
  const int arow = blockIdx.x * 64 + w * 16 + (lane & 15);
  const size_t rowoff = (arow < NN) ? (size_t)arow * FIN : 0;
  const float* xp = x + rowoff + (lane >> 4) * 8;
  f32x4 acc0 = {0.f, 0.f, 0.f, 0.f}, acc1 = acc0, acc2 = acc0, acc3 = acc0;
#pragma unroll
  for (int ks = 0; ks < 16; ++ks) {
    const float4 xa = *(const float4*)(xp);
    const float4 xb = *(const float4*)(xp + 4);
    xp += 32;
    uint4 ad;
    ad.x = cvt_pk_bf16(xa.x, xa.y);
    ad.y = cvt_pk_bf16(xa.z, xa.w);
    ad.z = cvt_pk_bf16(xb.x, xb.y);
    ad.w = cvt_pk_bf16(xb.z, xb.w);
    const short8 af = __builtin_bit_cast(short8, ad);
    const short8 b0 = *(const short8*)(W1p + ((size_t)(ks * 4 + 0) * 64 + lane) * 8);
    const short8 b1f = *(const short8*)(W1p + ((size_t)(ks * 4 + 1) * 64 + lane) * 8);
    const short8 b2 = *(const short8*)(W1p + ((size_t)(ks * 4 + 2) * 64 + lane) * 8);
    const short8 b3 = *(const short8*)(W1p + ((size_t)(ks * 4 + 3) * 64 + lane) * 8);
    acc0 = __builtin_amdgcn_mfma_f32_16x16x32_bf16(af, b0, acc0, 0, 0, 0);
    acc1 = __builtin_amdgcn_mfma_f32_16x16x32_bf16(af, b1f, acc1, 0, 0, 0);
    acc2 = __builtin_amdgcn_mfma_f32_16x16x32_bf16(af, b2, acc2, 0, 0, 0);
    acc3 = __builtin_amdgcn_mfma_f32_16x16x32_bf16(af, b3, acc3, 0, 0, 0);
  }
  // C/D layout: col = lane&15, row = (lane>>4)*4 + i   [m89]
  const int orow = blockIdx.x * 64 + w * 16 + (lane >> 4) * 4;
  const int ocol = lane & 15;
#define EPI(NB, ACC)                                                        \
  {                                                                         \
    const float bias = b1[NB * 16 + ocol];                                  \
    _Pragma("unroll") for (int i = 0; i < 4; ++i) {                         \
      const int r = orow + i;                                               \
      if (r < NN) {                                                         \
        const float v = fmaxf(ACC[i] + bias, 0.f);                          \
        R0[(size_t)r * HID + NB * 16 + ocol] = v;                           \
        R0b[(size_t)r * HID + NB * 16 + ocol] = bf16rne(v);                 \
      }                                                                     \
    }                                                                       \
  }
  EPI(0, acc0) EPI(1, acc1) EPI(2, acc2) EPI(3, acc3)
#undef EPI
}

// ---------------------------------------------------------------------------
// Kernel 2: build CSR rowptr from row-sorted COO with zero-val padding.
// ---------------------------------------------------------------------------
__global__ void build_rowptr_kernel(const int* __restrict__ row,
                                    const float* __restrict__ val,
                                    const int E, int* __restrict__ ptr) {
  const int e = blockIdx.x * blockDim.x + threadIdx.x;
  if (e >= E) return;
  const int c = (val[e] != 0.f) ? row[e] : NN;
  const int p = (e == 0) ? -1 : ((val[e - 1] != 0.f) ? row[e - 1] : NN);
  for (int r = p + 1; r <= c; ++r) ptr[r] = e;
  if (e == E - 1) {
    for (int r = c + 1; r <= NN; ++r) ptr[r] = E;
  }
}

// ---------------------------------------------------------------------------
// Segmented dot, 2 edges per VMEM on bf16 R.  Metadata staged to wave-private
// LDS; lanes 0-31 even edges, 32-63 odd edges, 2 features per lane.
// ONLY change vs round-6 (passing) version: u32 voffset + uniform base
// (saddr form) instead of (size_t) offset arithmetic.
// ---------------------------------------------------------------------------
template <int BLK>
__device__ __forceinline__ float2 seg_pair(const int* __restrict__ col,
                                           const float* __restrict__ val,
                                           int s, int t,
                                           const char* __restrict__ Rbc,
                                           uint2* __restrict__ meta,
                                           const int lane, const unsigned laneoff) {
  float a0 = 0.f, a1 = 0.f;
  const int half = lane >> 5;
  for (int e = s; e < t; e += BLK) {
    const int idx = e + lane;
    if (lane < BLK) {
      unsigned cw = 0u, vw = 0u;
      if (idx < t) { cw = (unsigned)col[idx]; vw = __float_as_uint(val[idx]); }
      meta[lane] = make_uint2(cw, vw);
    }
#pragma unroll
    for (int i = 0; i < BLK / 2; ++i) {
      const uint2 m = meta[2 * i + half];
      const float v = __uint_as_float(m.y);
      const unsigned off = m.x * 128u + laneoff;         // v_lshl_add_u32
      const unsigned gw = *(const unsigned*)(Rbc + off); // saddr load
      a0 = fmaf(v, __uint_as_float(gw << 16), a0);
      a1 = fmaf(v, __uint_as_float(gw & 0xffff0000u), a1);
    }
  }
  return make_float2(a0, a1);
}

// ---------------------------------------------------------------------------
// Kernel 3: fused dual-SpMM + max.  One wave per row.
// OUTMODE 0: write bf16 only (round 1).  OUTMODE 1: write f32 only (round 2).
// ---------------------------------------------------------------------------
template <int OUTMODE>
__global__ __launch_bounds__(256) void agg_kernel(
    const int* __restrict__ c1, const float* __restrict__ v1, const int* __restrict__ p1,
    const int* __restrict__ c2, const float* __restrict__ v2, const int* __restrict__ p2,
    const unsigned short* __restrict__ Rb,
    float* __restrict__ outf, unsigned short* __restrict__ outb) {
  __shared__ uint2 meta[4][64];
  const int wslot = threadIdx.x >> 6;
  const int wid = (int)((blockIdx.x * blockDim.x + threadIdx.x) >> 6);
  if (wid >= NN) return;
  const int lane = threadIdx.x & 63;
  const unsigned laneoff = (unsigned)(lane & 31) << 2;
  const char* Rbc = (const char*)Rb;
  const float2 h1 = seg_pair<16>(c1, v1, p1[wid], p1[wid + 1], Rbc, meta[wslot], lane, laneoff);
  const float2 h2 = seg_pair<64>(c2, v2, p2[wid], p2[wid + 1], Rbc, meta[wslot], lane, laneoff);
  const float t1e = h1.x + __shfl_xor(h1.x, 32, 64);
  const float t1o = h1.y + __shfl_xor(h1.y, 32, 64);
  const float t2e = h2.x + __shfl_xor(h2.x, 32, 64);
  const float t2o = h2.y + __shfl_xor(h2.y, 32, 64);
  const int half = lane >> 5;
  const float r = half ? fmaxf(t1o, t2o) : fmaxf(t1e, t2e);
  const size_t oidx = (size_t)wid * HID + 2 * (lane & 31) + half;
  if (OUTMODE == 0) outb[oidx] = bf16rne(r);
  else              outf[oidx] = r;
}

// ---------------------------------------------------------------------------
// Kernel 4: out = log_softmax(concat(R0, R1(bf16), R2) @ W2 + b2)  [f32 path]
// ---------------------------------------------------------------------------
__global__ void final_kernel(const float* __restrict__ R0,
                             const unsigned short* __restrict__ R1b,
                             const float* __restrict__ R2,
                             const float* __restrict__ W2,
                             const float* __restrict__ b2, float* __restrict__ out) {
  __shared__ float w2s[192 * 32];  // 24 KB
  __shared__ float fs[8][192];     // 6 KB
  const int t = threadIdx.x;
  const int node0 = blockIdx.x * 8;
  for (int i = t; i < 192 * 32; i += 256) w2s[i] = W2[i];
  for (int i = t; i < 8 * 192; i += 256) {
    const int n = i / 192, k = i % 192;
    const int node = node0 + n;
    float v = 0.f;
    if (node < NN) {
      v = (k < 64)  ? R0[(size_t)node * 64 + k]
        : (k < 128) ? bf2f(R1b[(size_t)node * 64 + (k - 64)])
                    : R2[(size_t)node * 64 + (k - 128)];
    }
    fs[n][k] = v;
  }
  __syncthreads();
  const int n = t >> 5, c = t & 31;
  const int node = node0 + n;
  float acc = b2[c];
#pragma unroll 8
  for (int k = 0; k < 192; ++k) acc += fs[n][k] * w2s[k * 32 + c];
  float m = acc;
  for (int off = 16; off; off >>= 1) m = fmaxf(m, __shfl_xor(m, off, 32));
  const float ex = __expf(acc - m);
  float ssum = ex;
  for (int off = 16; off; off >>= 1) ssum += __shfl_xor(ssum, off, 32);
  if (node < NN) out[(size_t)node * 32 + c] = (acc - m) - __logf(ssum);
}

// ---------------------------------------------------------------------------
extern "C" void kernel_launch(void* const* d_in, const int* in_sizes, int n_in,
                              void* d_out, int out_size, void* d_ws, size_t ws_size,
                              hipStream_t stream) {
  const float* x  = (const float*)d_in[0];
  const int*   e1r = (const int*)d_in[1];
  const int*   e1c = (const int*)d_in[2];
  const float* e1v = (const float*)d_in[3];
  const int*   e2r = (const int*)d_in[4];
  const int*   e2c = (const int*)d_in[5];
  const float* e2v = (const float*)d_in[6];
  const float* W1 = (const float*)d_in[7];
  const float* b1 = (const float*)d_in[8];
  const float* W2 = (const float*)d_in[9];
  const float* b2 = (const float*)d_in[10];
  float* out = (float*)d_out;
  const int E1 = in_sizes[1];
  const int E2 = in_sizes[4];

  char* wsb = (char*)d_ws;
  const size_t RSZ = (size_t)NN * HID;
  // layout (bytes): R0 f32 | R2 f32 | R0b bf16 | R1b bf16 | p1 | p2 | W1p
  const size_t need = RSZ * 4 * 2 + RSZ * 2 * 2 + 2 * (NN + 1) * sizeof(int)
                    + (size_t)FIN * HID * 2;
  if (ws_size < need) return;  // fail loud (wrong out), not OOB
  float*          R0  = (float*)wsb;
  float*          R2  = (float*)(wsb + RSZ * 4);
  unsigned short* R0b = (unsigned short*)(wsb + RSZ * 8);
  unsigned short* R1b = (unsigned short*)(wsb + RSZ * 8 + RSZ * 2);
  int*            p1  = (int*)(wsb + RSZ * 8 + RSZ * 4);
  int*            p2  = p1 + (NN + 1);
  unsigned short* W1p = (unsigned short*)(p2 + (NN + 1));

  // 0) pack W1 to bf16 fragment layout
  w1_pack_kernel<<<16, 256, 0, stream>>>(W1, W1p);

  // 1) relu(x @ W1 + b1) -> R0 f32 + R0b bf16 (MFMA, single-frag r6 version)
  gemm1_relu_kernel<<<(NN + 63) / 64, 256, 0, stream>>>(x, W1p, b1, R0, R0b);

  // 2) CSR rowptr for both graphs
  build_rowptr_kernel<<<(E1 + 255) / 256, 256, 0, stream>>>(e1r, e1v, E1, p1);
  build_rowptr_kernel<<<(E2 + 255) / 256, 256, 0, stream>>>(e2r, e2v, E2, p2);

  // 3) two rounds of fused dual-SpMM + max (bf16 gathers)
  const int aggb = (NN * 64) / 256;
  agg_kernel<0><<<aggb, 256, 0, stream>>>(e1c, e1v, p1, e2c, e2v, p2, R0b, (float*)nullptr, R1b);
  agg_kernel<1><<<aggb, 256, 0, stream>>>(e1c, e1v, p1, e2c, e2v, p2, R1b, R2, (unsigned short*)nullptr);

  // 4) final classifier + log_softmax (f32)
  final_kernel<<<(NN + 7) / 8, 256, 0, stream>>>(R0, R1b, R2, W2, b2, out);
}

// Round 13
// 355.772 us; speedup vs baseline: 4.2363x; 1.1136x over previous
//
#include <hip/hip_runtime.h>

#define NN 50000
#define FIN 512
#define HID 64
#define NC 32

typedef __attribute__((ext_vector_type(8))) short short8;
typedef __attribute__((ext_vector_type(4))) float f32x4;

__device__ __forceinline__ unsigned short bf16rne(float f) {
  unsigned u = __float_as_uint(f);
  u = u + 0x7FFFu + ((u >> 16) & 1u);
  return (unsigned short)(u >> 16);
}
__device__ __forceinline__ unsigned cvt_pk_bf16(float lo, float hi) {
  unsigned d;
  asm("v_cvt_pk_bf16_f32 %0, %1, %2" : "=v"(d) : "v"(lo), "v"(hi));
  return d;
}

// ---------------------------------------------------------------------------
// Kernel 0: pack W1 (512x64) and W2 (192x32) into bf16 MFMA B-frag layout.
// Fragment for lane l: col = nb*16 + (l&15), k = ks*32 + (l>>4)*8 + j.
// (W1 part identical to the passing w1_pack_kernel; W2 part re-derived:
//  W2[k][c] at W2[k*NC + c], fragment index ks*2 + nb stored at t2*8.)
// ---------------------------------------------------------------------------
__global__ void pack_kernel(const float* __restrict__ W1, const float* __restrict__ W2,
                            unsigned short* __restrict__ W1p,
                            unsigned short* __restrict__ W2p) {
  const int t = blockIdx.x * blockDim.x + threadIdx.x;
  if (t < 16 * 4 * 64) {                      // W1: 16 ks x 4 nb x 64 lanes
    const int lane = t & 63, nb = (t >> 6) & 3, ks = t >> 8;
    const int col = nb * 16 + (lane & 15);
    const int k0 = ks * 32 + (lane >> 4) * 8;
    uint4 d;
    d.x = cvt_pk_bf16(W1[(size_t)(k0 + 0) * HID + col], W1[(size_t)(k0 + 1) * HID + col]);
    d.y = cvt_pk_bf16(W1[(size_t)(k0 + 2) * HID + col], W1[(size_t)(k0 + 3) * HID + col]);
    d.z = cvt_pk_bf16(W1[(size_t)(k0 + 4) * HID + col], W1[(size_t)(k0 + 5) * HID + col]);
    d.w = cvt_pk_bf16(W1[(size_t)(k0 + 6) * HID + col], W1[(size_t)(k0 + 7) * HID + col]);
    *(uint4*)(W1p + (size_t)t * 8) = d;
  } else if (t < 4096 + 6 * 2 * 64) {         // W2: 6 ks x 2 nb x 64 lanes
    const int t2 = t - 4096;
    const int lane = t2 & 63, nb = (t2 >> 6) & 1, ks = t2 >> 7;
    const int col = nb * 16 + (lane & 15);
    const int k0 = ks * 32 + (lane >> 4) * 8;
    uint4 d;
    d.x = cvt_pk_bf16(W2[(size_t)(k0 + 0) * NC + col], W2[(size_t)(k0 + 1) * NC + col]);
    d.y = cvt_pk_bf16(W2[(size_t)(k0 + 2) * NC + col], W2[(size_t)(k0 + 3) * NC + col]);
    d.z = cvt_pk_bf16(W2[(size_t)(k0 + 4) * NC + col], W2[(size_t)(k0 + 5) * NC + col]);
    d.w = cvt_pk_bf16(W2[(size_t)(k0 + 6) * NC + col], W2[(size_t)(k0 + 7) * NC + col]);
    *(uint4*)(W2p + (size_t)t2 * 8) = d;
  }
}

// ---------------------------------------------------------------------------
// Kernel 1: R0b = bf16(relu(x @ W1 + b1)) via mfma_f32_16x16x32_bf16.
// 4 waves/block; wave w owns rows [blk*64 + w*16, +16), all 64 cols.
// (Proven single-fragment structure; only change vs r12: no f32 store.)
// ---------------------------------------------------------------------------
__global__ __launch_bounds__(256) void gemm1_relu_kernel(
    const float* __restrict__ x, const unsigned short* __restrict__ W1p,
    const float* __restrict__ b1, unsigned short* __restrict__ R0b) {
  const int t = threadIdx.x;
  const int w = t >> 6, lane = t & 63;
  const int arow = blockIdx.x * 64 + w * 16 + (lane & 15);
  const size_t rowoff = (arow < NN) ? (size_t)arow * FIN : 0;
  const float* xp = x + rowoff + (lane >> 4) * 8;
  f32x4 acc0 = {0.f, 0.f, 0.f, 0.f}, acc1 = acc0, acc2 = acc0, acc3 = acc0;
#pragma unroll
  for (int ks = 0; ks < 16; ++ks) {
    const float4 xa = *(const float4*)(xp);
    const float4 xb = *(const float4*)(xp + 4);
    xp += 32;
    uint4 ad;
    ad.x = cvt_pk_bf16(xa.x, xa.y);
    ad.y = cvt_pk_bf16(xa.z, xa.w);
    ad.z = cvt_pk_bf16(xb.x, xb.y);
    ad.w = cvt_pk_bf16(xb.z, xb.w);
    const short8 af = __builtin_bit_cast(short8, ad);
    const short8 b0 = *(const short8*)(W1p + ((size_t)(ks * 4 + 0) * 64 + lane) * 8);
    const short8 b1f = *(const short8*)(W1p + ((size_t)(ks * 4 + 1) * 64 + lane) * 8);
    const short8 b2 = *(const short8*)(W1p + ((size_t)(ks * 4 + 2) * 64 + lane) * 8);
    const short8 b3 = *(const short8*)(W1p + ((size_t)(ks * 4 + 3) * 64 + lane) * 8);
    acc0 = __builtin_amdgcn_mfma_f32_16x16x32_bf16(af, b0, acc0, 0, 0, 0);
    acc1 = __builtin_amdgcn_mfma_f32_16x16x32_bf16(af, b1f, acc1, 0, 0, 0);
    acc2 = __builtin_amdgcn_mfma_f32_16x16x32_bf16(af, b2, acc2, 0, 0, 0);
    acc3 = __builtin_amdgcn_mfma_f32_16x16x32_bf16(af, b3, acc3, 0, 0, 0);
  }
  // C/D layout: col = lane&15, row = (lane>>4)*4 + i
  const int orow = blockIdx.x * 64 + w * 16 + (lane >> 4) * 4;
  const int ocol = lane & 15;
#define EPI(NB, ACC)                                                        \
  {                                                                         \
    const float bias = b1[NB * 16 + ocol];                                  \
    _Pragma("unroll") for (int i = 0; i < 4; ++i) {                         \
      const int r = orow + i;                                               \
      if (r < NN) {                                                         \
        const float v = fmaxf(ACC[i] + bias, 0.f);                          \
        R0b[(size_t)r * HID + NB * 16 + ocol] = bf16rne(v);                 \
      }                                                                     \
    }                                                                       \
  }
  EPI(0, acc0) EPI(1, acc1) EPI(2, acc2) EPI(3, acc3)
#undef EPI
}

// ---------------------------------------------------------------------------
// Kernel 2: build CSR rowptr from row-sorted COO with zero-val padding.
// ---------------------------------------------------------------------------
__global__ void build_rowptr_kernel(const int* __restrict__ row,
                                    const float* __restrict__ val,
                                    const int E, int* __restrict__ ptr) {
  const int e = blockIdx.x * blockDim.x + threadIdx.x;
  if (e >= E) return;
  const int c = (val[e] != 0.f) ? row[e] : NN;
  const int p = (e == 0) ? -1 : ((val[e - 1] != 0.f) ? row[e - 1] : NN);
  for (int r = p + 1; r <= c; ++r) ptr[r] = e;
  if (e == E - 1) {
    for (int r = c + 1; r <= NN; ++r) ptr[r] = E;
  }
}

// ---------------------------------------------------------------------------
// Segmented dot, 2 edges per VMEM on bf16 R (saddr form, verified r12).
// ---------------------------------------------------------------------------
template <int BLK>
__device__ __forceinline__ float2 seg_pair(const int* __restrict__ col,
                                           const float* __restrict__ val,
                                           int s, int t,
                                           const char* __restrict__ Rbc,
                                           uint2* __restrict__ meta,
                                           const int lane, const unsigned laneoff) {
  float a0 = 0.f, a1 = 0.f;
  const int half = lane >> 5;
  for (int e = s; e < t; e += BLK) {
    const int idx = e + lane;
    if (lane < BLK) {
      unsigned cw = 0u, vw = 0u;
      if (idx < t) { cw = (unsigned)col[idx]; vw = __float_as_uint(val[idx]); }
      meta[lane] = make_uint2(cw, vw);
    }
#pragma unroll
    for (int i = 0; i < BLK / 2; ++i) {
      const uint2 m = meta[2 * i + half];
      const float v = __uint_as_float(m.y);
      const unsigned off = m.x * 128u + laneoff;
      const unsigned gw = *(const unsigned*)(Rbc + off);
      a0 = fmaf(v, __uint_as_float(gw << 16), a0);
      a1 = fmaf(v, __uint_as_float(gw & 0xffff0000u), a1);
    }
  }
  return make_float2(a0, a1);
}

// ---------------------------------------------------------------------------
// Kernel 3: fused dual-SpMM + max.  One wave per row; bf16 in, bf16 out.
// ---------------------------------------------------------------------------
__global__ __launch_bounds__(256) void agg_kernel(
    const int* __restrict__ c1, const float* __restrict__ v1, const int* __restrict__ p1,
    const int* __restrict__ c2, const float* __restrict__ v2, const int* __restrict__ p2,
    const unsigned short* __restrict__ Rb, unsigned short* __restrict__ outb) {
  __shared__ uint2 meta[4][64];
  const int wslot = threadIdx.x >> 6;
  const int wid = (int)((blockIdx.x * blockDim.x + threadIdx.x) >> 6);
  if (wid >= NN) return;
  const int lane = threadIdx.x & 63;
  const unsigned laneoff = (unsigned)(lane & 31) << 2;
  const char* Rbc = (const char*)Rb;
  const float2 h1 = seg_pair<16>(c1, v1, p1[wid], p1[wid + 1], Rbc, meta[wslot], lane, laneoff);
  const float2 h2 = seg_pair<64>(c2, v2, p2[wid], p2[wid + 1], Rbc, meta[wslot], lane, laneoff);
  const float t1e = h1.x + __shfl_xor(h1.x, 32, 64);
  const float t1o = h1.y + __shfl_xor(h1.y, 32, 64);
  const float t2e = h2.x + __shfl_xor(h2.x, 32, 64);
  const float t2o = h2.y + __shfl_xor(h2.y, 32, 64);
  const int half = lane >> 5;
  const float r = half ? fmaxf(t1o, t2o) : fmaxf(t1e, t2e);
  outb[(size_t)wid * HID + 2 * (lane & 31) + half] = bf16rne(r);
}

// ---------------------------------------------------------------------------
// Kernel 4: out = log_softmax([R0b R1b R2b] @ W2 + b2) via MFMA.
// Wave handles 16 nodes; K=192 in 6 steps (2 fragments per K-step source
// half); softmax across the 16-lane column group (shfl_xor offsets 1..8
// keep lane>>4 invariant).  All frag layouts proven in gemm1.
// ---------------------------------------------------------------------------
__global__ __launch_bounds__(256) void final_kernel(
    const unsigned short* __restrict__ R0b, const unsigned short* __restrict__ R1b,
    const unsigned short* __restrict__ R2b, const unsigned short* __restrict__ W2p,
    const float* __restrict__ b2, float* __restrict__ out) {
  const int t = threadIdx.x;
  const int w = t >> 6, lane = t & 63;
  const int node0 = blockIdx.x * 64 + w * 16;
  const int arow = node0 + (lane & 15);
  const size_t rbase = (size_t)(arow < NN ? arow : 0) * HID + (lane >> 4) * 8;
  f32x4 acc0 = {0.f, 0.f, 0.f, 0.f}, acc1 = acc0;
#define FSTEP(KS, SRC)                                                          \
  {                                                                             \
    const short8 af = *(const short8*)(SRC + rbase + (KS & 1) * 32);            \
    const short8 bf0 = *(const short8*)(W2p + ((size_t)(KS * 2 + 0) * 64 + lane) * 8); \
    const short8 bf1 = *(const short8*)(W2p + ((size_t)(KS * 2 + 1) * 64 + lane) * 8); \
    acc0 = __builtin_amdgcn_mfma_f32_16x16x32_bf16(af, bf0, acc0, 0, 0, 0);     \
    acc1 = __builtin_amdgcn_mfma_f32_16x16x32_bf16(af, bf1, acc1, 0, 0, 0);     \
  }
  FSTEP(0, R0b) FSTEP(1, R0b) FSTEP(2, R1b) FSTEP(3, R1b) FSTEP(4, R2b) FSTEP(5, R2b)
#undef FSTEP
  const float b2v0 = b2[lane & 15];
  const float b2v1 = b2[16 + (lane & 15)];
#pragma unroll
  for (int i = 0; i < 4; ++i) {
    const float l0 = acc0[i] + b2v0;
    const float l1 = acc1[i] + b2v1;
    float m = fmaxf(l0, l1);
    for (int off = 1; off < 16; off <<= 1) m = fmaxf(m, __shfl_xor(m, off, 64));
    float s = __expf(l0 - m) + __expf(l1 - m);
    for (int off = 1; off < 16; off <<= 1) s += __shfl_xor(s, off, 64);
    const float lse = m + __logf(s);
    const int r = node0 + (lane >> 4) * 4 + i;
    if (r < NN) {
      out[(size_t)r * NC + (lane & 15)] = l0 - lse;
      out[(size_t)r * NC + 16 + (lane & 15)] = l1 - lse;
    }
  }
}

// ---------------------------------------------------------------------------
extern "C" void kernel_launch(void* const* d_in, const int* in_sizes, int n_in,
                              void* d_out, int out_size, void* d_ws, size_t ws_size,
                              hipStream_t stream) {
  const float* x  = (const float*)d_in[0];
  const int*   e1r = (const int*)d_in[1];
  const int*   e1c = (const int*)d_in[2];
  const float* e1v = (const float*)d_in[3];
  const int*   e2r = (const int*)d_in[4];
  const int*   e2c = (const int*)d_in[5];
  const float* e2v = (const float*)d_in[6];
  const float* W1 = (const float*)d_in[7];
  const float* b1 = (const float*)d_in[8];
  const float* W2 = (const float*)d_in[9];
  const float* b2 = (const float*)d_in[10];
  float* out = (float*)d_out;
  const int E1 = in_sizes[1];
  const int E2 = in_sizes[4];

  char* wsb = (char*)d_ws;
  const size_t RSZ = (size_t)NN * HID;
  // layout (bytes): R0b | R1b | R2b (bf16) | p1 | p2 | W1p | W2p
  const size_t need = RSZ * 2 * 3 + 2 * (NN + 1) * sizeof(int)
                    + (size_t)4096 * 16 + (size_t)768 * 16;
  if (ws_size < need) return;  // fail loud (wrong out), not OOB
  unsigned short* R0b = (unsigned short*)wsb;
  unsigned short* R1b = (unsigned short*)(wsb + RSZ * 2);
  unsigned short* R2b = (unsigned short*)(wsb + RSZ * 4);
  int*            p1  = (int*)(wsb + RSZ * 6);
  int*            p2  = p1 + (NN + 1);
  unsigned short* W1p = (unsigned short*)(p2 + (NN + 1));
  unsigned short* W2p = W1p + (size_t)4096 * 8;

  // 0) pack W1/W2 to bf16 fragment layout
  pack_kernel<<<19, 256, 0, stream>>>(W1, W2, W1p, W2p);

  // 1) R0b = bf16(relu(x @ W1 + b1)), MFMA (proven single-frag)
  gemm1_relu_kernel<<<(NN + 63) / 64, 256, 0, stream>>>(x, W1p, b1, R0b);

  // 2) CSR rowptr for both graphs
  build_rowptr_kernel<<<(E1 + 255) / 256, 256, 0, stream>>>(e1r, e1v, E1, p1);
  build_rowptr_kernel<<<(E2 + 255) / 256, 256, 0, stream>>>(e2r, e2v, E2, p2);

  // 3) two rounds of fused dual-SpMM + max (bf16 gathers, bf16 out)
  const int aggb = (NN * 64) / 256;
  agg_kernel<<<aggb, 256, 0, stream>>>(e1c, e1v, p1, e2c, e2v, p2, R0b, R1b);
  agg_kernel<<<aggb, 256, 0, stream>>>(e1c, e1v, p1, e2c, e2v, p2, R1b, R2b);

  // 4) final classifier + log_softmax (MFMA)
  final_kernel<<<(NN + 63) / 64, 256, 0, stream>>>(R0b, R1b, R2b, W2p, b2, out);
}